// Round 1
// baseline (815.372 us; speedup 1.0000x reference)
//
#include <hip/hip_runtime.h>

// LIF forward scan:
//   u = 0.5*u + x[t]; s = (u >= 1); u -= s; out[t] = s
// T=16 sequential steps per independent spatial position.
// N_POS = BATCH*C*H*W = 32*64*32*32 = 2,097,152 independent sequences.
// Layout: x[t*N_POS + i]. One thread owns 4 consecutive i (float4),
// carries u in registers across t. Fully coalesced, 16 B/lane.
//
// v2: explicit two-phase structure — batch 8 timestep loads into registers,
// then run the dependent u-chain + stores, twice. Guarantees 8 outstanding
// global loads per wave (MLP) independent of the serial u carry chain,
// while keeping register file usage ~56 VGPR (8 waves/SIMD, full occupancy).

#define T_STEPS 16
#define N_POS   (32 * 64 * 32 * 32)       // 2,097,152
#define N4      (N_POS / 4)               // 524,288 float4 groups per t
#define HALF    8                          // timesteps per load batch

__global__ __launch_bounds__(256) void lif_scan_kernel(
    const float4* __restrict__ x, float4* __restrict__ out)
{
    const int gid = blockIdx.x * blockDim.x + threadIdx.x;  // 0 .. N4-1
    const float4* __restrict__ xp = x + gid;
    float4* __restrict__ op       = out + gid;

    float4 u = make_float4(0.f, 0.f, 0.f, 0.f);
    float4 xt[HALF];

    #pragma unroll
    for (int h = 0; h < 2; ++h) {
        // Phase 1: issue all 8 loads of this half — independent, 8 in flight.
        #pragma unroll
        for (int k = 0; k < HALF; ++k) {
            xt[k] = xp[(size_t)(h * HALF + k) * (size_t)N4];
        }
        // Phase 2: dependent u-chain + stores.
        #pragma unroll
        for (int k = 0; k < HALF; ++k) {
            float4 s;
            u.x = 0.5f * u.x + xt[k].x; s.x = (u.x >= 1.0f) ? 1.0f : 0.0f; u.x -= s.x;
            u.y = 0.5f * u.y + xt[k].y; s.y = (u.y >= 1.0f) ? 1.0f : 0.0f; u.y -= s.y;
            u.z = 0.5f * u.z + xt[k].z; s.z = (u.z >= 1.0f) ? 1.0f : 0.0f; u.z -= s.z;
            u.w = 0.5f * u.w + xt[k].w; s.w = (u.w >= 1.0f) ? 1.0f : 0.0f; u.w -= s.w;
            op[(size_t)(h * HALF + k) * (size_t)N4] = s;
        }
    }
}

extern "C" void kernel_launch(void* const* d_in, const int* in_sizes, int n_in,
                              void* d_out, int out_size, void* d_ws, size_t ws_size,
                              hipStream_t stream)
{
    const float4* x  = (const float4*)d_in[0];   // inputs [T*B, 64, 32, 32] f32
    float4* out      = (float4*)d_out;           // spikes, same shape, f32
    // d_in[1] (random_tangents) is unused by the reference output.

    const int threads = 256;
    const int blocks  = N4 / threads;            // 524288 / 256 = 2048
    lif_scan_kernel<<<blocks, threads, 0, stream>>>(x, out);
}